// Round 8
// baseline (111.405 us; speedup 1.0000x reference)
//
#include <hip/hip_runtime.h>
#include <stdint.h>

#pragma clang fp contract(off)

#define NMS_B 8
#define NMS_N 4096
#define ROIS 256

typedef unsigned long long u64;
typedef unsigned int u32;

__device__ __forceinline__ int lds_slot(int e) { return e + (e >> 2); }  // 4-way max bank aliasing

// suppression predicate (exact arithmetic of the proven K2):
// true => row box suppresses col box (IoU > 0.5); symmetric.
__device__ __forceinline__ bool sup_pred(float4 rc, float rh, float4 cc, float ch) {
    float iw = fmaxf(fminf(rc.z, cc.z) - fmaxf(rc.x, cc.x), 0.0f);
    float ih = fmaxf(fminf(rc.w, cc.w) - fmaxf(rc.y, cc.y), 0.0f);
    float inter = iw * ih;
    return inter > fmaf(-0.5f, inter, rh + ch);   // 1.5*inter > haR+haC
}

// ---------------------------------------------------------------------------
// v10 = v9 with three serialization fixes (v9 post-mortem: kernel 55us is
// barrier/atomic-bound, not VALU-bound):
//  1. Phase C sort: 4 elems/thread on 256 threads (K1a's proven layout) ->
//     6 block barriers instead of 20; j=4..128 via shfl, j<=2 in-thread.
//     Same compare-exchange network -> bit-identical order.
//  2. Phase B: wave-aggregated append (ballot + popc prefix + 1 atomic per
//     wave per round = 64 atomics vs ~516 serialized on one LDS address).
//  3. Phase E: 72 half-word tasks (unit x 32-bit half) over 16 waves ->
//     11% imbalance (was 33%), disjoint u32 writes, no atomics; F reads
//     h as u64 pairs (little-endian: lo half = bits 0..31).
// LDS regions de-aliased into one 68KB arena (1 block/CU anyway).
// Fallback (full v8 path) verbatim; never runs on bench data.
// ---------------------------------------------------------------------------
__global__ __launch_bounds__(1024, 1) void nms_all(
        const float* __restrict__ in, u32* __restrict__ sortedIdx,
        float4* __restrict__ crn, float* __restrict__ ha,
        float* __restrict__ outp) {
    __shared__ u64 sm[8736];                 // 68.25 KB arena
    __shared__ int kept[ROIS];
    __shared__ int s_selCount, s_B, s_needFull;
    const int b = blockIdx.x, t = threadIdx.x;
    const int lane = t & 63, wid = t >> 6;
    const size_t base = (size_t)b * NMS_N;

    // fast-path region map (u64 offsets into sm):
    u32*    hist   = (u32*)sm;               // [4096]  0..2047
    u32*    pp     = (u32*)(sm + 2048);      // [1024]  2048..2559
    u32*    qq     = (u32*)(sm + 2560);      // [64]    2560..2591
    u64*    selKey = sm + 2592;              // [1024]  2592..3615
    u64*    sortA  = sm + 3616;              // [1280]  3616..4895
    float4* crn_s  = (float4*)(sm + 4896);   // [512]   4896..5919
    float*  ha_s   = (float*)(sm + 5920);    // [512]   5920..6175
    u32*    sidx_s = (u32*)(sm + 6176);      // [512]   6176..6431
    u32*    h32    = (u32*)(sm + 6432);      // [36][64][2] 6432..8735

    // ---- Phase A: histogram ----
    float sc[4];
    int   bk[4];
    #pragma unroll
    for (int r = 0; r < 4; ++r) {
        int e = t + 1024 * r;
        sc[r] = in[(base + e) * 5];
        int bb = (int)(sc[r] * 4096.0f);     // monotone in score
        bb = bb < 0 ? 0 : bb;
        bk[r] = bb > 4095 ? 4095 : bb;
    }
    for (int i = t; i < 4096; i += 1024) hist[i] = 0;
    if (t == 0) { s_selCount = 0; s_needFull = 0; }
    __syncthreads();
    #pragma unroll
    for (int r = 0; r < 4; ++r) atomicAdd(&hist[bk[r]], 1u);
    __syncthreads();
    pp[t] = hist[4 * t] + hist[4 * t + 1] + hist[4 * t + 2] + hist[4 * t + 3];
    __syncthreads();
    if (t < 64) {
        u32 s = 0;
        for (int i = 0; i < 16; ++i) s += pp[16 * t + i];
        qq[t] = s;
    }
    __syncthreads();
    if (t == 0) {                            // hierarchical suffix search for B
        int acc = 0, L = 0;
        for (int l = 63; l >= 0; --l) { acc += (int)qq[l]; if (acc >= 512) { L = l; break; } }
        int rem = 512 - (acc - (int)qq[L]);
        int acc2 = 0, T = 16 * L;
        for (int i = 16 * L + 15; i >= 16 * L; --i) { acc2 += (int)pp[i]; if (acc2 >= rem) { T = i; break; } }
        int rem2 = rem - (acc2 - (int)pp[T]);
        int acc3 = 0, B = 4 * T;
        for (int bb = 4 * T + 3; bb >= 4 * T; --bb) { acc3 += (int)hist[bb]; if (acc3 >= rem2) { B = bb; break; } }
        s_B = B;
    }
    __syncthreads();

    // ---- Phase B: wave-aggregated selection append ----
    const int B = s_B;
    #pragma unroll
    for (int r = 0; r < 4; ++r) {
        bool pred = (bk[r] >= B);
        u64 m = __ballot(pred);
        u32 cnt = (u32)__popcll(m);
        int wbase = 0;
        if (lane == 0 && cnt) wbase = atomicAdd(&s_selCount, (int)cnt);
        wbase = __shfl(wbase, 0, 64);
        if (pred) {
            int slot = wbase + (int)__popcll(m & ((1ULL << lane) - 1ULL));
            if (slot < 1024) {
                int e = t + 1024 * r;
                selKey[slot] = ((u64)(~__float_as_uint(sc[r])) << 32) | (u32)e;
            }
        }
    }
    __syncthreads();
    const int selCount = s_selCount;
    const bool fullPath = (selCount > 1024); // uniform

    if (!fullPath) {
        // ---- Phase C: bitonic 1024, 4 elems/thread on 256 threads ----
        u64 key4[4];
        if (t < 256) {
            #pragma unroll
            for (int r = 0; r < 4; ++r) {
                int e = 4 * t + r;
                key4[r] = (e < selCount) ? selKey[e] : ~0ULL;   // pad sorts to end
            }
        }
        for (int k = 2; k <= 1024; k <<= 1) {
            int j = k >> 1;
            if (j >= 256) {                  // uniform in k -> uniform barriers
                if (t < 256) {
                    #pragma unroll
                    for (int r = 0; r < 4; ++r) sortA[lds_slot(4 * t + r)] = key4[r];
                }
                __syncthreads();
                for (; j >= 256; j >>= 1) {
                    if (t < 256) {
                        for (int el = t; el < 1024; el += 256) {
                            int p = el ^ j;
                            if (p > el) {
                                u64 a = sortA[lds_slot(el)], cc = sortA[lds_slot(p)];
                                bool up = ((el & k) == 0);
                                if ((a > cc) == up) { sortA[lds_slot(el)] = cc; sortA[lds_slot(p)] = a; }
                            }
                        }
                    }
                    __syncthreads();
                }
                if (t < 256) {
                    #pragma unroll
                    for (int r = 0; r < 4; ++r) key4[r] = sortA[lds_slot(4 * t + r)];
                }
            }
            if (t < 256) {                   // waves 0-3 only: no barriers inside
                for (; j >= 4; j >>= 1) {    // cross-lane via shfl_xor
                    int d = j >> 2;
                    #pragma unroll
                    for (int r = 0; r < 4; ++r) {
                        int e = 4 * t + r;
                        u64 mine = key4[r];
                        u64 part = __shfl_xor(mine, d, 64);
                        bool up = ((e & k) == 0);
                        bool lower = ((e & j) == 0);
                        u64 mn = (mine < part) ? mine : part;
                        u64 mx = (mine < part) ? part : mine;
                        key4[r] = (up == lower) ? mn : mx;
                    }
                }
                for (; j >= 1; j >>= 1) {    // j in {2,1}: in-thread
                    #pragma unroll
                    for (int r = 0; r < 4; ++r) {
                        int pr = r | j;
                        if (((r & j) == 0) && pr < 4) {
                            int e = 4 * t + r;
                            bool up = ((e & k) == 0);
                            u64 a = key4[r], cc = key4[pr];
                            if ((a > cc) == up) { key4[r] = cc; key4[pr] = a; }
                        }
                    }
                }
            }
        }
        if (t < 256) {
            #pragma unroll
            for (int r = 0; r < 4; ++r) selKey[4 * t + r] = key4[r];
        }
        __syncthreads();

        // ---- Phase D: corners for top 512 -> LDS ----
        if (t < 512) {
            u32 orig = (u32)selKey[t];
            const float* bp = in + (base + orig) * 5;
            float x = bp[1], y = bp[2], w = bp[3], h = bp[4];
            float ws_ = floorf(w * 0.5f), hs_ = floorf(h * 0.5f);
            float4 c4 = make_float4(x - ws_, y - hs_, x + ws_, y + hs_);
            crn_s[t] = c4;
            ha_s[t] = 0.5f * ((c4.z - c4.x) * (c4.w - c4.y));  // exact half-area
            sidx_s[t] = orig;
        }
        for (int r = t; r < ROIS; r += 1024) kept[r] = 0;
        __syncthreads();

        // ---- Phase E: 72 half-word tasks over 16 waves ----
        for (int tau = wid; tau < 72; tau += 16) {
            int u = tau >> 1, hf = tau & 1;
            int kr = 0;
            while ((kr + 1) * (kr + 2) / 2 <= u) ++kr;
            int w = u - kr * (kr + 1) / 2;
            float4 myc = crn_s[64 * kr + lane];
            float  myh = ha_s[64 * kr + lane];
            u32 word = 0;
            const int q0 = hf * 32;
            #pragma unroll 4
            for (int q = 0; q < 32; ++q) {   // uniform -> LDS broadcast
                bool p = sup_pred(crn_s[64 * w + q0 + q], ha_s[64 * w + q0 + q], myc, myh);
                word |= (u32)(p ? 1u : 0u) << q;
            }
            h32[(u * 64 + lane) * 2 + hf] = word;   // disjoint u32, no atomics
        }
        __syncthreads();

        // ---- Phase F: ballot-chain scan, wave 0 ----
        if (t < 64) {
            u64* h_lds = (u64*)h32;          // h_lds[u*64+lane], lo half bits 0..31
            int count = 0;
            u32 f[8];
            #pragma unroll
            for (int k = 0; k < 8; ++k) f[k] = 1u;
            bool done = false;
            #pragma unroll
            for (int g = 0; g < 8; ++g) {
                if (!done) {
                    u64 hgg = h_lds[(g * (g + 1) / 2 + g) * 64 + lane];
                    u64 kb = 0;
                    u64 avail = __ballot(f[g] != 0);
                    while (avail != 0 && count < ROIS) {
                        int r = __builtin_ctzll(avail);        // wave-uniform
                        if (lane == 0) kept[count] = g * 64 + r;
                        ++count;
                        kb |= 1ULL << r;
                        u32 bit = (u32)(hgg >> r) & 1u;
                        f[g] &= (bit ^ 1u) & (u32)(lane != r);
                        avail = __ballot(f[g] != 0);
                    }
                    if (count >= ROIS) {
                        done = true;
                    } else {
                        #pragma unroll
                        for (int k2 = g + 1; k2 < 8; ++k2)
                            f[k2] &= (u32)((h_lds[(k2 * (k2 + 1) / 2 + g) * 64 + lane] & kb) == 0);
                    }
                }
            }
            if (t == 0) s_needFull = (count >= ROIS) ? 0 : 1;
        }
        __syncthreads();
    }

    // ======== FULL FALLBACK (correctness-only; never on bench data) ========
    if (fullPath || s_needFull) {
        // P1: full 4096 bitonic sort (v8 verbatim)
        u64 key[4];
        #pragma unroll
        for (int r = 0; r < 4; ++r) {
            int e = 4 * t + r;
            float s = in[(base + e) * 5];
            key[r] = ((u64)(~__float_as_uint(s)) << 32) | (u32)e;
        }
        for (int k = 2; k <= 4096; k <<= 1) {
            int j = k >> 1;
            if (j >= 256) {
                #pragma unroll
                for (int r = 0; r < 4; ++r) sm[lds_slot(4 * t + r)] = key[r];
                __syncthreads();
                for (; j >= 256; j >>= 1) {
                    for (int el = t; el < 4096; el += 1024) {
                        int p = el ^ j;
                        if (p > el) {
                            u64 a = sm[lds_slot(el)], cc = sm[lds_slot(p)];
                            bool up = ((el & k) == 0);
                            if ((a > cc) == up) { sm[lds_slot(el)] = cc; sm[lds_slot(p)] = a; }
                        }
                    }
                    __syncthreads();
                }
                #pragma unroll
                for (int r = 0; r < 4; ++r) key[r] = sm[lds_slot(4 * t + r)];
            }
            for (; j >= 4; j >>= 1) {
                int d = j >> 2;
                #pragma unroll
                for (int r = 0; r < 4; ++r) {
                    int e = 4 * t + r;
                    u64 mine = key[r];
                    u64 part = __shfl_xor(mine, d, 64);
                    bool up = ((e & k) == 0);
                    bool lower = ((e & j) == 0);
                    u64 mn = (mine < part) ? mine : part;
                    u64 mx = (mine < part) ? part : mine;
                    key[r] = (up == lower) ? mn : mx;
                }
            }
            for (; j >= 1; j >>= 1) {
                #pragma unroll
                for (int r = 0; r < 4; ++r) {
                    int pr = r | j;
                    if (((r & j) == 0) && pr < 4) {
                        int e = 4 * t + r;
                        bool up = ((e & k) == 0);
                        u64 a = key[r], cc = key[pr];
                        if ((a > cc) == up) { key[r] = cc; key[pr] = a; }
                    }
                }
            }
        }
        __syncthreads();

        u64*    h2 = sm;                      // [36][64]
        float4* crn2 = (float4*)(sm + 2304);  // [512]
        float*  ha2  = (float*)(sm + 2304 + 1024);

        // P2
        #pragma unroll
        for (int r = 0; r < 4; ++r) {
            int e = 4 * t + r;
            u32 orig = (u32)key[r];
            const float* bp = in + (base + orig) * 5;
            float x = bp[1], y = bp[2], w = bp[3], h = bp[4];
            float ws_ = floorf(w * 0.5f), hs_ = floorf(h * 0.5f);
            float4 c4 = make_float4(x - ws_, y - hs_, x + ws_, y + hs_);
            float hv = 0.5f * ((c4.z - c4.x) * (c4.w - c4.y));
            size_t g = base + e;
            sortedIdx[g] = orig;
            crn[g] = c4;
            ha[g] = hv;
            if (e < 512) { crn2[e] = c4; ha2[e] = hv; }
        }
        for (int r = t; r < ROIS; r += 1024) kept[r] = 0;
        __syncthreads();

        // P3
        for (int u = wid; u < 36; u += 16) {
            int kr = 0;
            while ((kr + 1) * (kr + 2) / 2 <= u) ++kr;
            int w = u - kr * (kr + 1) / 2;
            float4 myc = crn2[64 * kr + lane];
            float  myh = ha2[64 * kr + lane];
            u64 word = 0;
            #pragma unroll 4
            for (int q = 0; q < 64; ++q) {
                bool p = sup_pred(crn2[64 * w + q], ha2[64 * w + q], myc, myh);
                word |= ((u64)(p ? 1u : 0u)) << q;
            }
            h2[(size_t)u * 64 + lane] = word;
        }
        __syncthreads();

        // P4+P5
        if (t < 64) {
            int count = 0;
            u32 f[8];
            #pragma unroll
            for (int k = 0; k < 8; ++k) f[k] = 1u;
            bool done = false;
            #pragma unroll
            for (int g = 0; g < 8; ++g) {
                if (!done) {
                    u64 hgg = h2[(size_t)(g * (g + 1) / 2 + g) * 64 + lane];
                    u64 kb = 0;
                    u64 avail = __ballot(f[g] != 0);
                    while (avail != 0 && count < ROIS) {
                        int r = __builtin_ctzll(avail);
                        if (lane == 0) kept[count] = g * 64 + r;
                        ++count;
                        kb |= 1ULL << r;
                        u32 bit = (u32)(hgg >> r) & 1u;
                        f[g] &= (bit ^ 1u) & (u32)(lane != r);
                        avail = __ballot(f[g] != 0);
                    }
                    if (count >= ROIS) {
                        done = true;
                    } else {
                        #pragma unroll
                        for (int k2 = g + 1; k2 < 8; ++k2)
                            f[k2] &= (u32)((h2[(size_t)(k2 * (k2 + 1) / 2 + g) * 64 + lane] & kb) == 0);
                    }
                }
            }
            if (count < ROIS) {
                for (int Wp = 4; Wp < 32 && count < ROIS; ++Wp) {
                    const int cLo = 128 * Wp + lane, cHi = cLo + 64;
                    float4 cL = crn[base + cLo]; float hL = ha[base + cLo];
                    float4 cH = crn[base + cHi]; float hH = ha[base + cHi];
                    u32 fLo = 1u, fHi = 1u;
                    for (int j2 = 0; j2 < count; ++j2) {
                        int pos = kept[j2];
                        float4 kc = crn[base + pos]; float kh = ha[base + pos];
                        fLo &= (u32)(!sup_pred(kc, kh, cL, hL));
                        fHi &= (u32)(!sup_pred(kc, kh, cH, hH));
                    }
                    u64 curLo0 = 0, curHi0 = 0, curHi1 = 0;
                    for (int r = 0; r < 64; ++r) {
                        float4 rc = crn[base + 128 * Wp + r]; float rh = ha[base + 128 * Wp + r];
                        curLo0 |= ((u64)(sup_pred(rc, rh, cL, hL) ? 1u : 0u)) << r;
                        curHi0 |= ((u64)(sup_pred(rc, rh, cH, hH) ? 1u : 0u)) << r;
                    }
                    for (int r = 0; r < 64; ++r) {
                        float4 rc = crn[base + 128 * Wp + 64 + r]; float rh = ha[base + 128 * Wp + 64 + r];
                        curHi1 |= ((u64)(sup_pred(rc, rh, cH, hH) ? 1u : 0u)) << r;
                    }
                    u64 availLo = __ballot(fLo != 0);
                    while (availLo != 0 && count < ROIS) {
                        int r = __builtin_ctzll(availLo);
                        if (lane == 0) kept[count] = Wp * 128 + r;
                        ++count;
                        fLo &= (u32)(((curLo0 >> r) & 1ULL) ^ 1ULL) & (u32)(lane != r);
                        fHi &= (u32)(((curHi0 >> r) & 1ULL) ^ 1ULL);
                        availLo = __ballot(fLo != 0);
                    }
                    u64 availHi = __ballot(fHi != 0);
                    while (availHi != 0 && count < ROIS) {
                        int r = __builtin_ctzll(availHi);
                        if (lane == 0) kept[count] = Wp * 128 + 64 + r;
                        ++count;
                        fHi &= (u32)(((curHi1 >> r) & 1ULL) ^ 1ULL) & (u32)(lane != r);
                        availHi = __ballot(fHi != 0);
                    }
                }
            }
        }
    }
    __syncthreads();

    // ---- output ----
    const bool usedFull = fullPath || (s_needFull != 0);
    if (t < ROIS) {
        int pos = kept[t];
        int orig = usedFull ? (int)sortedIdx[base + pos]
                            : (int)((u32*)(sm + 6176))[pos];
        const float* bp = in + (base + orig) * 5;
        ((float4*)outp)[(size_t)b * ROIS + t] =
            make_float4(bp[1], bp[2], bp[3], bp[4]);
    }
}

extern "C" void kernel_launch(void* const* d_in, const int* in_sizes, int n_in,
                              void* d_out, int out_size, void* d_ws, size_t ws_size,
                              hipStream_t stream) {
    const float* in = (const float*)d_in[0];
    float* out = (float*)d_out;
    char* ws = (char*)d_ws;

    u32* sortedIdx = (u32*)ws;                 size_t off = (size_t)NMS_B * NMS_N * 4;
    float4* crn = (float4*)(ws + off);         off += (size_t)NMS_B * NMS_N * 16;
    float* ha = (float*)(ws + off);            off += (size_t)NMS_B * NMS_N * 4;

    nms_all<<<NMS_B, 1024, 0, stream>>>(in, sortedIdx, crn, ha, out);
}

// Round 9
// 105.392 us; speedup vs baseline: 1.0571x; 1.0571x over previous
//
#include <hip/hip_runtime.h>
#include <stdint.h>

#pragma clang fp contract(off)

#define NMS_B 8
#define NMS_N 4096
#define ROIS 256
#define SEL_TAU 0.85f

typedef unsigned long long u64;
typedef unsigned int u32;

__device__ __forceinline__ int lds_slot(int e) { return e + (e >> 2); }  // 4-way max bank aliasing

// suppression predicate (exact arithmetic of the proven K2):
// true => row box suppresses col box (IoU > 0.5); symmetric.
__device__ __forceinline__ bool sup_pred(float4 rc, float rh, float4 cc, float ch) {
    float iw = fmaxf(fminf(rc.z, cc.z) - fmaxf(rc.x, cc.x), 0.0f);
    float ih = fmaxf(fminf(rc.w, cc.w) - fmaxf(rc.y, cc.y), 0.0f);
    float inter = iw * ih;
    return inter > fmaf(-0.5f, inter, rh + ch);   // 1.5*inter > haR+haC
}

// ---------------------------------------------------------------------------
// v11. v10 post-mortem: 256-thread sort = 1 wave/SIMD for 52 shfl stages ->
// +10us; at occupancy-1, waves beat barriers. v11:
//  - Phase C reverted to v9's EXACT 16-wave 1-elem/thread bitonic.
//  - Histogram DELETED: fixed threshold tau=0.85 (uniform scores -> ~614
//    selected). Correct for any input: selCount<512 or >1024 -> exact full
//    fallback. Removes 4096 LDS atomics, 16KB zeroing, 2 barriers, and the
//    t==0 serial suffix search (~84 dependent LDS reads).
//  - Kept from v10: wave-aggregated append (B), 72-task balanced E.
// Fallback (full v8 path) verbatim; never runs on bench data.
// ---------------------------------------------------------------------------
__global__ __launch_bounds__(1024, 1) void nms_all(
        const float* __restrict__ in, u32* __restrict__ sortedIdx,
        float4* __restrict__ crn, float* __restrict__ ha,
        float* __restrict__ outp) {
    __shared__ u64 sm[6144];                 // 48 KB arena, phase-mapped
    __shared__ int kept[ROIS];
    __shared__ int s_selCount, s_needFull;
    const int b = blockIdx.x, t = threadIdx.x;
    const int lane = t & 63, wid = t >> 6;
    const size_t base = (size_t)b * NMS_N;

    // fast-path region map (u64 offsets into sm):
    u64*    selKey = sm;                     // [1024]  0..1023
    u64*    sortA  = sm + 1024;              // [1280]  1024..2303 (slot(1023)=1278)
    float4* crn_s  = (float4*)(sm + 2304);   // [512]   2304..3327
    float*  ha_s   = (float*)(sm + 3328);    // [512]   3328..3583
    u32*    sidx_s = (u32*)(sm + 3584);      // [512]   3584..3839
    u32*    h32    = (u32*)(sm + 3840);      // [36][64][2] 3840..6143

    // ---- Phase A': load scores; no histogram ----
    float sc[4];
    #pragma unroll
    for (int r = 0; r < 4; ++r) {
        int e = t + 1024 * r;
        sc[r] = in[(base + e) * 5];
    }
    if (t == 0) { s_selCount = 0; s_needFull = 0; }
    __syncthreads();

    // ---- Phase B: wave-aggregated selection append (score >= tau) ----
    #pragma unroll
    for (int r = 0; r < 4; ++r) {
        bool pred = (sc[r] >= SEL_TAU);
        u64 m = __ballot(pred);
        u32 cnt = (u32)__popcll(m);
        int wbase = 0;
        if (lane == 0 && cnt) wbase = atomicAdd(&s_selCount, (int)cnt);
        wbase = __shfl(wbase, 0, 64);
        if (pred) {
            int slot = wbase + (int)__popcll(m & ((1ULL << lane) - 1ULL));
            if (slot < 1024) {
                int e = t + 1024 * r;
                selKey[slot] = ((u64)(~__float_as_uint(sc[r])) << 32) | (u32)e;
            }
        }
    }
    __syncthreads();
    const int selCount = s_selCount;
    const bool fullPath = (selCount < 512) || (selCount > 1024);   // uniform

    if (!fullPath) {
        // ---- Phase C: bitonic 1024, 1 elem/thread on 16 waves (v9 form) ----
        u64 kk = (t < selCount) ? selKey[t] : ~0ULL;   // pad sorts to end
        for (int k = 2; k <= 1024; k <<= 1) {
            int j = k >> 1;
            for (; j >= 64; j >>= 1) {       // cross-wave via LDS
                sortA[lds_slot(t)] = kk;
                __syncthreads();
                u64 part = sortA[lds_slot(t ^ j)];
                bool up = ((t & k) == 0), lower = ((t & j) == 0);
                u64 mn = kk < part ? kk : part, mx = kk < part ? part : kk;
                kk = (up == lower) ? mn : mx;
                __syncthreads();
            }
            for (; j >= 1; j >>= 1) {        // j<=32: in-wave shfl
                u64 part = __shfl_xor(kk, j, 64);
                bool up = ((t & k) == 0), lower = ((t & j) == 0);
                u64 mn = kk < part ? kk : part, mx = kk < part ? part : kk;
                kk = (up == lower) ? mn : mx;
            }
        }
        selKey[t] = kk;                      // sorted ascending
        __syncthreads();

        // ---- Phase D: corners for top 512 -> LDS ----
        if (t < 512) {
            u32 orig = (u32)selKey[t];
            const float* bp = in + (base + orig) * 5;
            float x = bp[1], y = bp[2], w = bp[3], h = bp[4];
            float ws_ = floorf(w * 0.5f), hs_ = floorf(h * 0.5f);
            float4 c4 = make_float4(x - ws_, y - hs_, x + ws_, y + hs_);
            crn_s[t] = c4;
            ha_s[t] = 0.5f * ((c4.z - c4.x) * (c4.w - c4.y));  // exact half-area
            sidx_s[t] = orig;
        }
        for (int r = t; r < ROIS; r += 1024) kept[r] = 0;
        __syncthreads();

        // ---- Phase E: 72 half-word tasks over 16 waves ----
        for (int tau = wid; tau < 72; tau += 16) {
            int u = tau >> 1, hf = tau & 1;
            int kr = 0;
            while ((kr + 1) * (kr + 2) / 2 <= u) ++kr;
            int w = u - kr * (kr + 1) / 2;
            float4 myc = crn_s[64 * kr + lane];
            float  myh = ha_s[64 * kr + lane];
            u32 word = 0;
            const int q0 = hf * 32;
            #pragma unroll 4
            for (int q = 0; q < 32; ++q) {   // uniform -> LDS broadcast
                bool p = sup_pred(crn_s[64 * w + q0 + q], ha_s[64 * w + q0 + q], myc, myh);
                word |= (u32)(p ? 1u : 0u) << q;
            }
            h32[(u * 64 + lane) * 2 + hf] = word;   // disjoint u32, no atomics
        }
        __syncthreads();

        // ---- Phase F: ballot-chain scan, wave 0 ----
        if (t < 64) {
            u64* h_lds = (u64*)h32;          // h_lds[u*64+lane]
            int count = 0;
            u32 f[8];
            #pragma unroll
            for (int k = 0; k < 8; ++k) f[k] = 1u;
            bool done = false;
            #pragma unroll
            for (int g = 0; g < 8; ++g) {
                if (!done) {
                    u64 hgg = h_lds[(g * (g + 1) / 2 + g) * 64 + lane];
                    u64 kb = 0;
                    u64 avail = __ballot(f[g] != 0);
                    while (avail != 0 && count < ROIS) {
                        int r = __builtin_ctzll(avail);        // wave-uniform
                        if (lane == 0) kept[count] = g * 64 + r;
                        ++count;
                        kb |= 1ULL << r;
                        u32 bit = (u32)(hgg >> r) & 1u;
                        f[g] &= (bit ^ 1u) & (u32)(lane != r);
                        avail = __ballot(f[g] != 0);
                    }
                    if (count >= ROIS) {
                        done = true;
                    } else {
                        #pragma unroll
                        for (int k2 = g + 1; k2 < 8; ++k2)
                            f[k2] &= (u32)((h_lds[(k2 * (k2 + 1) / 2 + g) * 64 + lane] & kb) == 0);
                    }
                }
            }
            if (t == 0) s_needFull = (count >= ROIS) ? 0 : 1;
        }
        __syncthreads();
    }

    // ======== FULL FALLBACK (correctness-only; never on bench data) ========
    if (fullPath || s_needFull) {
        // P1: full 4096 bitonic sort (v8 verbatim)
        u64 key[4];
        #pragma unroll
        for (int r = 0; r < 4; ++r) {
            int e = 4 * t + r;
            float s = in[(base + e) * 5];
            key[r] = ((u64)(~__float_as_uint(s)) << 32) | (u32)e;
        }
        for (int k = 2; k <= 4096; k <<= 1) {
            int j = k >> 1;
            if (j >= 256) {
                #pragma unroll
                for (int r = 0; r < 4; ++r) sm[lds_slot(4 * t + r)] = key[r];
                __syncthreads();
                for (; j >= 256; j >>= 1) {
                    for (int el = t; el < 4096; el += 1024) {
                        int p = el ^ j;
                        if (p > el) {
                            u64 a = sm[lds_slot(el)], cc = sm[lds_slot(p)];
                            bool up = ((el & k) == 0);
                            if ((a > cc) == up) { sm[lds_slot(el)] = cc; sm[lds_slot(p)] = a; }
                        }
                    }
                    __syncthreads();
                }
                #pragma unroll
                for (int r = 0; r < 4; ++r) key[r] = sm[lds_slot(4 * t + r)];
            }
            for (; j >= 4; j >>= 1) {
                int d = j >> 2;
                #pragma unroll
                for (int r = 0; r < 4; ++r) {
                    int e = 4 * t + r;
                    u64 mine = key[r];
                    u64 part = __shfl_xor(mine, d, 64);
                    bool up = ((e & k) == 0);
                    bool lower = ((e & j) == 0);
                    u64 mn = (mine < part) ? mine : part;
                    u64 mx = (mine < part) ? part : mine;
                    key[r] = (up == lower) ? mn : mx;
                }
            }
            for (; j >= 1; j >>= 1) {
                #pragma unroll
                for (int r = 0; r < 4; ++r) {
                    int pr = r | j;
                    if (((r & j) == 0) && pr < 4) {
                        int e = 4 * t + r;
                        bool up = ((e & k) == 0);
                        u64 a = key[r], cc = key[pr];
                        if ((a > cc) == up) { key[r] = cc; key[pr] = a; }
                    }
                }
            }
        }
        __syncthreads();

        u64*    h2 = sm;                      // [36][64]
        float4* crn2 = (float4*)(sm + 2304);  // [512]
        float*  ha2  = (float*)(sm + 2304 + 1024);

        // P2
        #pragma unroll
        for (int r = 0; r < 4; ++r) {
            int e = 4 * t + r;
            u32 orig = (u32)key[r];
            const float* bp = in + (base + orig) * 5;
            float x = bp[1], y = bp[2], w = bp[3], h = bp[4];
            float ws_ = floorf(w * 0.5f), hs_ = floorf(h * 0.5f);
            float4 c4 = make_float4(x - ws_, y - hs_, x + ws_, y + hs_);
            float hv = 0.5f * ((c4.z - c4.x) * (c4.w - c4.y));
            size_t g = base + e;
            sortedIdx[g] = orig;
            crn[g] = c4;
            ha[g] = hv;
            if (e < 512) { crn2[e] = c4; ha2[e] = hv; }
        }
        for (int r = t; r < ROIS; r += 1024) kept[r] = 0;
        __syncthreads();

        // P3
        for (int u = wid; u < 36; u += 16) {
            int kr = 0;
            while ((kr + 1) * (kr + 2) / 2 <= u) ++kr;
            int w = u - kr * (kr + 1) / 2;
            float4 myc = crn2[64 * kr + lane];
            float  myh = ha2[64 * kr + lane];
            u64 word = 0;
            #pragma unroll 4
            for (int q = 0; q < 64; ++q) {
                bool p = sup_pred(crn2[64 * w + q], ha2[64 * w + q], myc, myh);
                word |= ((u64)(p ? 1u : 0u)) << q;
            }
            h2[(size_t)u * 64 + lane] = word;
        }
        __syncthreads();

        // P4+P5
        if (t < 64) {
            int count = 0;
            u32 f[8];
            #pragma unroll
            for (int k = 0; k < 8; ++k) f[k] = 1u;
            bool done = false;
            #pragma unroll
            for (int g = 0; g < 8; ++g) {
                if (!done) {
                    u64 hgg = h2[(size_t)(g * (g + 1) / 2 + g) * 64 + lane];
                    u64 kb = 0;
                    u64 avail = __ballot(f[g] != 0);
                    while (avail != 0 && count < ROIS) {
                        int r = __builtin_ctzll(avail);
                        if (lane == 0) kept[count] = g * 64 + r;
                        ++count;
                        kb |= 1ULL << r;
                        u32 bit = (u32)(hgg >> r) & 1u;
                        f[g] &= (bit ^ 1u) & (u32)(lane != r);
                        avail = __ballot(f[g] != 0);
                    }
                    if (count >= ROIS) {
                        done = true;
                    } else {
                        #pragma unroll
                        for (int k2 = g + 1; k2 < 8; ++k2)
                            f[k2] &= (u32)((h2[(size_t)(k2 * (k2 + 1) / 2 + g) * 64 + lane] & kb) == 0);
                    }
                }
            }
            if (count < ROIS) {
                for (int Wp = 4; Wp < 32 && count < ROIS; ++Wp) {
                    const int cLo = 128 * Wp + lane, cHi = cLo + 64;
                    float4 cL = crn[base + cLo]; float hL = ha[base + cLo];
                    float4 cH = crn[base + cHi]; float hH = ha[base + cHi];
                    u32 fLo = 1u, fHi = 1u;
                    for (int j2 = 0; j2 < count; ++j2) {
                        int pos = kept[j2];
                        float4 kc = crn[base + pos]; float kh = ha[base + pos];
                        fLo &= (u32)(!sup_pred(kc, kh, cL, hL));
                        fHi &= (u32)(!sup_pred(kc, kh, cH, hH));
                    }
                    u64 curLo0 = 0, curHi0 = 0, curHi1 = 0;
                    for (int r = 0; r < 64; ++r) {
                        float4 rc = crn[base + 128 * Wp + r]; float rh = ha[base + 128 * Wp + r];
                        curLo0 |= ((u64)(sup_pred(rc, rh, cL, hL) ? 1u : 0u)) << r;
                        curHi0 |= ((u64)(sup_pred(rc, rh, cH, hH) ? 1u : 0u)) << r;
                    }
                    for (int r = 0; r < 64; ++r) {
                        float4 rc = crn[base + 128 * Wp + 64 + r]; float rh = ha[base + 128 * Wp + 64 + r];
                        curHi1 |= ((u64)(sup_pred(rc, rh, cH, hH) ? 1u : 0u)) << r;
                    }
                    u64 availLo = __ballot(fLo != 0);
                    while (availLo != 0 && count < ROIS) {
                        int r = __builtin_ctzll(availLo);
                        if (lane == 0) kept[count] = Wp * 128 + r;
                        ++count;
                        fLo &= (u32)(((curLo0 >> r) & 1ULL) ^ 1ULL) & (u32)(lane != r);
                        fHi &= (u32)(((curHi0 >> r) & 1ULL) ^ 1ULL);
                        availLo = __ballot(fLo != 0);
                    }
                    u64 availHi = __ballot(fHi != 0);
                    while (availHi != 0 && count < ROIS) {
                        int r = __builtin_ctzll(availHi);
                        if (lane == 0) kept[count] = Wp * 128 + 64 + r;
                        ++count;
                        fHi &= (u32)(((curHi1 >> r) & 1ULL) ^ 1ULL) & (u32)(lane != r);
                        availHi = __ballot(fHi != 0);
                    }
                }
            }
        }
    }
    __syncthreads();

    // ---- output ----
    const bool usedFull = fullPath || (s_needFull != 0);
    if (t < ROIS) {
        int pos = kept[t];
        int orig = usedFull ? (int)sortedIdx[base + pos]
                            : (int)((u32*)(sm + 3584))[pos];
        const float* bp = in + (base + orig) * 5;
        ((float4*)outp)[(size_t)b * ROIS + t] =
            make_float4(bp[1], bp[2], bp[3], bp[4]);
    }
}

extern "C" void kernel_launch(void* const* d_in, const int* in_sizes, int n_in,
                              void* d_out, int out_size, void* d_ws, size_t ws_size,
                              hipStream_t stream) {
    const float* in = (const float*)d_in[0];
    float* out = (float*)d_out;
    char* ws = (char*)d_ws;

    u32* sortedIdx = (u32*)ws;                 size_t off = (size_t)NMS_B * NMS_N * 4;
    float4* crn = (float4*)(ws + off);         off += (size_t)NMS_B * NMS_N * 16;
    float* ha = (float*)(ws + off);            off += (size_t)NMS_B * NMS_N * 4;

    nms_all<<<NMS_B, 1024, 0, stream>>>(in, sortedIdx, crn, ha, out);
}

// Round 10
// 104.682 us; speedup vs baseline: 1.0642x; 1.0068x over previous
//
#include <hip/hip_runtime.h>
#include <stdint.h>

#pragma clang fp contract(off)

#define NMS_B 8
#define NMS_N 4096
#define ROIS 256
#define SEL_TAU 0.85f

typedef unsigned long long u64;
typedef unsigned int u32;

__device__ __forceinline__ int lds_slot(int e) { return e + (e >> 2); }  // 4-way max bank aliasing

__device__ __forceinline__ u64 rdlane_u64(u64 v, int l) {
    u32 lo = (u32)__builtin_amdgcn_readlane((int)(u32)v, l);
    u32 hi = (u32)__builtin_amdgcn_readlane((int)(u32)(v >> 32), l);
    return ((u64)hi << 32) | lo;
}

// suppression predicate (exact arithmetic of the proven K2):
// true => row box suppresses col box (IoU > 0.5); symmetric.
__device__ __forceinline__ bool sup_pred(float4 rc, float rh, float4 cc, float ch) {
    float iw = fmaxf(fminf(rc.z, cc.z) - fmaxf(rc.x, cc.x), 0.0f);
    float ih = fmaxf(fminf(rc.w, cc.w) - fmaxf(rc.y, cc.y), 0.0f);
    float inter = iw * ih;
    return inter > fmaf(-0.5f, inter, rh + ch);   // 1.5*inter > haR+haC
}

// ---------------------------------------------------------------------------
// v12 = v11 + two cycle cuts (wall ~= cycles at ~1 GHz; clock doesn't boost
// at 8/256 CUs — explains every round's ~2.5x model underestimate):
//  1. Phase F: scalar suppression chain. h is SYMMETRIC, so the word
//     "lanes suppressed by kept r" == readlane(hgg, r). Loop is
//     ctz -> readlane -> 64-bit andn (~25-30 cy/iter) with ONE ballot per
//     group, replacing per-iter {per-lane flag update + ballot} (~60-80 cy).
//     Bit-identical kept sequence (~(1<<r) == old lane!=r self-clear).
//  2. C->D register handoff: after the 1-elem/thread bitonic, thread t
//     holds sorted[t] in kk — selKey write-back, its barrier, and D's 512
//     LDS reads deleted.
// Everything else identical to v11. Fallback (full v8 path) verbatim.
// ---------------------------------------------------------------------------
__global__ __launch_bounds__(1024, 1) void nms_all(
        const float* __restrict__ in, u32* __restrict__ sortedIdx,
        float4* __restrict__ crn, float* __restrict__ ha,
        float* __restrict__ outp) {
    __shared__ u64 sm[6144];                 // 48 KB arena, phase-mapped
    __shared__ int kept[ROIS];
    __shared__ int s_selCount, s_needFull;
    const int b = blockIdx.x, t = threadIdx.x;
    const int lane = t & 63, wid = t >> 6;
    const size_t base = (size_t)b * NMS_N;

    // fast-path region map (u64 offsets into sm):
    u64*    selKey = sm;                     // [1024]  0..1023 (pre-sort staging)
    u64*    sortA  = sm + 1024;              // [1280]  1024..2303 (slot(1023)=1278)
    float4* crn_s  = (float4*)(sm + 2304);   // [512]   2304..3327
    float*  ha_s   = (float*)(sm + 3328);    // [512]   3328..3583
    u32*    sidx_s = (u32*)(sm + 3584);      // [512]   3584..3839
    u32*    h32    = (u32*)(sm + 3840);      // [36][64][2] 3840..6143

    // ---- Phase A': load scores; no histogram ----
    float sc[4];
    #pragma unroll
    for (int r = 0; r < 4; ++r) {
        int e = t + 1024 * r;
        sc[r] = in[(base + e) * 5];
    }
    if (t == 0) { s_selCount = 0; s_needFull = 0; }
    __syncthreads();

    // ---- Phase B: wave-aggregated selection append (score >= tau) ----
    #pragma unroll
    for (int r = 0; r < 4; ++r) {
        bool pred = (sc[r] >= SEL_TAU);
        u64 m = __ballot(pred);
        u32 cnt = (u32)__popcll(m);
        int wbase = 0;
        if (lane == 0 && cnt) wbase = atomicAdd(&s_selCount, (int)cnt);
        wbase = __shfl(wbase, 0, 64);
        if (pred) {
            int slot = wbase + (int)__popcll(m & ((1ULL << lane) - 1ULL));
            if (slot < 1024) {
                int e = t + 1024 * r;
                selKey[slot] = ((u64)(~__float_as_uint(sc[r])) << 32) | (u32)e;
            }
        }
    }
    __syncthreads();
    const int selCount = s_selCount;
    const bool fullPath = (selCount < 512) || (selCount > 1024);   // uniform

    if (!fullPath) {
        // ---- Phase C: bitonic 1024, 1 elem/thread on 16 waves ----
        u64 kk = (t < selCount) ? selKey[t] : ~0ULL;   // pad sorts to end
        for (int k = 2; k <= 1024; k <<= 1) {
            int j = k >> 1;
            for (; j >= 64; j >>= 1) {       // cross-wave via LDS
                sortA[lds_slot(t)] = kk;
                __syncthreads();
                u64 part = sortA[lds_slot(t ^ j)];
                bool up = ((t & k) == 0), lower = ((t & j) == 0);
                u64 mn = kk < part ? kk : part, mx = kk < part ? part : kk;
                kk = (up == lower) ? mn : mx;
                __syncthreads();
            }
            for (; j >= 1; j >>= 1) {        // j<=32: in-wave shfl
                u64 part = __shfl_xor(kk, j, 64);
                bool up = ((t & k) == 0), lower = ((t & j) == 0);
                u64 mn = kk < part ? kk : part, mx = kk < part ? part : kk;
                kk = (up == lower) ? mn : mx;
            }
        }
        // thread t now holds sorted element t in kk — no write-back needed

        // ---- Phase D: corners for top 512 -> LDS (from register kk) ----
        if (t < 512) {
            u32 orig = (u32)kk;
            const float* bp = in + (base + orig) * 5;
            float x = bp[1], y = bp[2], w = bp[3], h = bp[4];
            float ws_ = floorf(w * 0.5f), hs_ = floorf(h * 0.5f);
            float4 c4 = make_float4(x - ws_, y - hs_, x + ws_, y + hs_);
            crn_s[t] = c4;
            ha_s[t] = 0.5f * ((c4.z - c4.x) * (c4.w - c4.y));  // exact half-area
            sidx_s[t] = orig;
        }
        for (int r = t; r < ROIS; r += 1024) kept[r] = 0;
        __syncthreads();

        // ---- Phase E: 72 half-word tasks over 16 waves ----
        for (int tau = wid; tau < 72; tau += 16) {
            int u = tau >> 1, hf = tau & 1;
            int kr = 0;
            while ((kr + 1) * (kr + 2) / 2 <= u) ++kr;
            int w = u - kr * (kr + 1) / 2;
            float4 myc = crn_s[64 * kr + lane];
            float  myh = ha_s[64 * kr + lane];
            u32 word = 0;
            const int q0 = hf * 32;
            #pragma unroll 4
            for (int q = 0; q < 32; ++q) {   // uniform -> LDS broadcast
                bool p = sup_pred(crn_s[64 * w + q0 + q], ha_s[64 * w + q0 + q], myc, myh);
                word |= (u32)(p ? 1u : 0u) << q;
            }
            h32[(u * 64 + lane) * 2 + hf] = word;   // disjoint u32, no atomics
        }
        __syncthreads();

        // ---- Phase F: scalar-chain scan, wave 0 ----
        if (t < 64) {
            u64* h_lds = (u64*)h32;          // h_lds[u*64+lane]
            int count = 0;
            u32 f[8];
            #pragma unroll
            for (int k = 0; k < 8; ++k) f[k] = 1u;
            bool done = false;
            #pragma unroll
            for (int g = 0; g < 8; ++g) {
                if (!done) {
                    u64 hgg = h_lds[(g * (g + 1) / 2 + g) * 64 + lane];
                    u64 kb = 0;
                    u64 avail = __ballot(f[g] != 0);   // one ballot per group
                    while (avail != 0 && count < ROIS) {
                        int r = __builtin_ctzll(avail);        // wave-uniform
                        if (lane == 0) kept[count] = g * 64 + r;
                        ++count;
                        kb |= 1ULL << r;
                        // symmetry: lanes suppressed by kept r == column r's word
                        u64 w = rdlane_u64(hgg, r);
                        avail &= ~(w | (1ULL << r));
                    }
                    if (count >= ROIS) {
                        done = true;
                    } else {
                        #pragma unroll
                        for (int k2 = g + 1; k2 < 8; ++k2)
                            f[k2] &= (u32)((h_lds[(k2 * (k2 + 1) / 2 + g) * 64 + lane] & kb) == 0);
                    }
                }
            }
            if (t == 0) s_needFull = (count >= ROIS) ? 0 : 1;
        }
        __syncthreads();
    }

    // ======== FULL FALLBACK (correctness-only; never on bench data) ========
    if (fullPath || s_needFull) {
        // P1: full 4096 bitonic sort (v8 verbatim)
        u64 key[4];
        #pragma unroll
        for (int r = 0; r < 4; ++r) {
            int e = 4 * t + r;
            float s = in[(base + e) * 5];
            key[r] = ((u64)(~__float_as_uint(s)) << 32) | (u32)e;
        }
        for (int k = 2; k <= 4096; k <<= 1) {
            int j = k >> 1;
            if (j >= 256) {
                #pragma unroll
                for (int r = 0; r < 4; ++r) sm[lds_slot(4 * t + r)] = key[r];
                __syncthreads();
                for (; j >= 256; j >>= 1) {
                    for (int el = t; el < 4096; el += 1024) {
                        int p = el ^ j;
                        if (p > el) {
                            u64 a = sm[lds_slot(el)], cc = sm[lds_slot(p)];
                            bool up = ((el & k) == 0);
                            if ((a > cc) == up) { sm[lds_slot(el)] = cc; sm[lds_slot(p)] = a; }
                        }
                    }
                    __syncthreads();
                }
                #pragma unroll
                for (int r = 0; r < 4; ++r) key[r] = sm[lds_slot(4 * t + r)];
            }
            for (; j >= 4; j >>= 1) {
                int d = j >> 2;
                #pragma unroll
                for (int r = 0; r < 4; ++r) {
                    int e = 4 * t + r;
                    u64 mine = key[r];
                    u64 part = __shfl_xor(mine, d, 64);
                    bool up = ((e & k) == 0);
                    bool lower = ((e & j) == 0);
                    u64 mn = (mine < part) ? mine : part;
                    u64 mx = (mine < part) ? part : mine;
                    key[r] = (up == lower) ? mn : mx;
                }
            }
            for (; j >= 1; j >>= 1) {
                #pragma unroll
                for (int r = 0; r < 4; ++r) {
                    int pr = r | j;
                    if (((r & j) == 0) && pr < 4) {
                        int e = 4 * t + r;
                        bool up = ((e & k) == 0);
                        u64 a = key[r], cc = key[pr];
                        if ((a > cc) == up) { key[r] = cc; key[pr] = a; }
                    }
                }
            }
        }
        __syncthreads();

        u64*    h2 = sm;                      // [36][64]
        float4* crn2 = (float4*)(sm + 2304);  // [512]
        float*  ha2  = (float*)(sm + 2304 + 1024);

        // P2
        #pragma unroll
        for (int r = 0; r < 4; ++r) {
            int e = 4 * t + r;
            u32 orig = (u32)key[r];
            const float* bp = in + (base + orig) * 5;
            float x = bp[1], y = bp[2], w = bp[3], h = bp[4];
            float ws_ = floorf(w * 0.5f), hs_ = floorf(h * 0.5f);
            float4 c4 = make_float4(x - ws_, y - hs_, x + ws_, y + hs_);
            float hv = 0.5f * ((c4.z - c4.x) * (c4.w - c4.y));
            size_t g = base + e;
            sortedIdx[g] = orig;
            crn[g] = c4;
            ha[g] = hv;
            if (e < 512) { crn2[e] = c4; ha2[e] = hv; }
        }
        for (int r = t; r < ROIS; r += 1024) kept[r] = 0;
        __syncthreads();

        // P3
        for (int u = wid; u < 36; u += 16) {
            int kr = 0;
            while ((kr + 1) * (kr + 2) / 2 <= u) ++kr;
            int w = u - kr * (kr + 1) / 2;
            float4 myc = crn2[64 * kr + lane];
            float  myh = ha2[64 * kr + lane];
            u64 word = 0;
            #pragma unroll 4
            for (int q = 0; q < 64; ++q) {
                bool p = sup_pred(crn2[64 * w + q], ha2[64 * w + q], myc, myh);
                word |= ((u64)(p ? 1u : 0u)) << q;
            }
            h2[(size_t)u * 64 + lane] = word;
        }
        __syncthreads();

        // P4+P5
        if (t < 64) {
            int count = 0;
            u32 f[8];
            #pragma unroll
            for (int k = 0; k < 8; ++k) f[k] = 1u;
            bool done = false;
            #pragma unroll
            for (int g = 0; g < 8; ++g) {
                if (!done) {
                    u64 hgg = h2[(size_t)(g * (g + 1) / 2 + g) * 64 + lane];
                    u64 kb = 0;
                    u64 avail = __ballot(f[g] != 0);
                    while (avail != 0 && count < ROIS) {
                        int r = __builtin_ctzll(avail);
                        if (lane == 0) kept[count] = g * 64 + r;
                        ++count;
                        kb |= 1ULL << r;
                        u32 bit = (u32)(hgg >> r) & 1u;
                        f[g] &= (bit ^ 1u) & (u32)(lane != r);
                        avail = __ballot(f[g] != 0);
                    }
                    if (count >= ROIS) {
                        done = true;
                    } else {
                        #pragma unroll
                        for (int k2 = g + 1; k2 < 8; ++k2)
                            f[k2] &= (u32)((h2[(size_t)(k2 * (k2 + 1) / 2 + g) * 64 + lane] & kb) == 0);
                    }
                }
            }
            if (count < ROIS) {
                for (int Wp = 4; Wp < 32 && count < ROIS; ++Wp) {
                    const int cLo = 128 * Wp + lane, cHi = cLo + 64;
                    float4 cL = crn[base + cLo]; float hL = ha[base + cLo];
                    float4 cH = crn[base + cHi]; float hH = ha[base + cHi];
                    u32 fLo = 1u, fHi = 1u;
                    for (int j2 = 0; j2 < count; ++j2) {
                        int pos = kept[j2];
                        float4 kc = crn[base + pos]; float kh = ha[base + pos];
                        fLo &= (u32)(!sup_pred(kc, kh, cL, hL));
                        fHi &= (u32)(!sup_pred(kc, kh, cH, hH));
                    }
                    u64 curLo0 = 0, curHi0 = 0, curHi1 = 0;
                    for (int r = 0; r < 64; ++r) {
                        float4 rc = crn[base + 128 * Wp + r]; float rh = ha[base + 128 * Wp + r];
                        curLo0 |= ((u64)(sup_pred(rc, rh, cL, hL) ? 1u : 0u)) << r;
                        curHi0 |= ((u64)(sup_pred(rc, rh, cH, hH) ? 1u : 0u)) << r;
                    }
                    for (int r = 0; r < 64; ++r) {
                        float4 rc = crn[base + 128 * Wp + 64 + r]; float rh = ha[base + 128 * Wp + 64 + r];
                        curHi1 |= ((u64)(sup_pred(rc, rh, cH, hH) ? 1u : 0u)) << r;
                    }
                    u64 availLo = __ballot(fLo != 0);
                    while (availLo != 0 && count < ROIS) {
                        int r = __builtin_ctzll(availLo);
                        if (lane == 0) kept[count] = Wp * 128 + r;
                        ++count;
                        fLo &= (u32)(((curLo0 >> r) & 1ULL) ^ 1ULL) & (u32)(lane != r);
                        fHi &= (u32)(((curHi0 >> r) & 1ULL) ^ 1ULL);
                        availLo = __ballot(fLo != 0);
                    }
                    u64 availHi = __ballot(fHi != 0);
                    while (availHi != 0 && count < ROIS) {
                        int r = __builtin_ctzll(availHi);
                        if (lane == 0) kept[count] = Wp * 128 + 64 + r;
                        ++count;
                        fHi &= (u32)(((curHi1 >> r) & 1ULL) ^ 1ULL) & (u32)(lane != r);
                        availHi = __ballot(fHi != 0);
                    }
                }
            }
        }
    }
    __syncthreads();

    // ---- output ----
    const bool usedFull = fullPath || (s_needFull != 0);
    if (t < ROIS) {
        int pos = kept[t];
        int orig = usedFull ? (int)sortedIdx[base + pos]
                            : (int)((u32*)(sm + 3584))[pos];
        const float* bp = in + (base + orig) * 5;
        ((float4*)outp)[(size_t)b * ROIS + t] =
            make_float4(bp[1], bp[2], bp[3], bp[4]);
    }
}

extern "C" void kernel_launch(void* const* d_in, const int* in_sizes, int n_in,
                              void* d_out, int out_size, void* d_ws, size_t ws_size,
                              hipStream_t stream) {
    const float* in = (const float*)d_in[0];
    float* out = (float*)d_out;
    char* ws = (char*)d_ws;

    u32* sortedIdx = (u32*)ws;                 size_t off = (size_t)NMS_B * NMS_N * 4;
    float4* crn = (float4*)(ws + off);         off += (size_t)NMS_B * NMS_N * 16;
    float* ha = (float*)(ws + off);            off += (size_t)NMS_B * NMS_N * 4;

    nms_all<<<NMS_B, 1024, 0, stream>>>(in, sortedIdx, crn, ha, out);
}